// Round 7
// baseline (5138.517 us; speedup 1.0000x reference)
//
#include <hip/hip_runtime.h>

#define DEV __device__ __forceinline__
typedef unsigned short us;
typedef __bf16 bf8 __attribute__((ext_vector_type(8)));
typedef float  f4  __attribute__((ext_vector_type(4)));

DEV us f2bf(float f){
  unsigned int u = __builtin_bit_cast(unsigned int, f);
  u = u + 0x7fffu + ((u >> 16) & 1u);
  return (us)(u >> 16);
}
DEV float sigm(float x){ return 1.f/(1.f + __expf(-x)); }
DEV bf8 ldb(const us* p){ return *reinterpret_cast<const bf8*>(p); }
DEV f4 mfma(bf8 a, bf8 b, f4 c){ return __builtin_amdgcn_mfma_f32_16x16x32_bf16(a, b, c, 0, 0, 0); }

// ---------------- workspace layout (bytes) — total ~172 MB
constexpr size_t OFF_WCAT0  = 0;                            // [2][1536][640] bf16 (K pad to 128-mult)
constexpr size_t OFF_WCAT1  = OFF_WCAT0 + 2ull*1536*640*2;  // [1536][1536] bf16
constexpr size_t OFF_W1R    = OFF_WCAT1 + 1536ull*1536*2;   // [1536][1024] bf16
constexpr size_t OFF_FC1W   = OFF_W1R   + 1536ull*1024*2;   // [256][1024] bf16
constexpr size_t OFF_FC2W   = OFF_FC1W  + 256ull*1024*2;    // [16][256] bf16
constexpr size_t OFF_BRZ0   = OFF_FC2W  + 16ull*256*2;      // [2][1024] f32
constexpr size_t OFF_BNIH0  = OFF_BRZ0  + 2*1024*4;         // [2][512]
constexpr size_t OFF_BNHH0  = OFF_BNIH0 + 2*512*4;          // [2][512]
constexpr size_t OFF_BRZ1   = OFF_BNHH0 + 2*512*4;          // [1024]
constexpr size_t OFF_BNIH1  = OFF_BRZ1  + 1024*4;           // [512]
constexpr size_t OFF_BNHH1  = OFF_BNIH1 + 512*4;            // [512]
constexpr size_t OFF_BRZ1R  = OFF_BNHH1 + 512*4;            // [1024]
constexpr size_t OFF_BNIH1R = OFF_BRZ1R + 1024*4;           // [512]
constexpr size_t OFF_BNHH1R = OFF_BNIH1R+ 512*4;            // [512]
constexpr size_t OFF_SC2    = OFF_BNHH1R+ 512*4;            // [256]
constexpr size_t OFF_SH2    = OFF_SC2   + 256*4;            // [256]
constexpr size_t OFF_FC2B   = OFF_SH2   + 256*4;            // [16]
constexpr size_t OFF_Y0B    = OFF_FC2B  + 64;               // [4096][28][512] bf16
constexpr size_t OFF_H0BF   = OFF_Y0B   + 4096ull*28*512*2; // [2pp][4096][512] bf16
constexpr size_t OFF_H0F32  = OFF_H0BF  + 2ull*4096*512*2;  // [4096][512] f32
constexpr size_t OFF_H1BF   = OFF_H0F32 + 4096ull*512*4;    // [2pp][4096][512] bf16
constexpr size_t OFF_H1F32  = OFF_H1BF  + 2ull*4096*512*2;  // [4096][512] f32
constexpr size_t OFF_H1BBF  = OFF_H1F32 + 4096ull*512*4;    // [4096][512] bf16

constexpr long PP = 4096ll*512;

// ---------------- K0: weight/bias prep ----------------
__global__ void prep_kernel(
  const float* __restrict__ Wih0, const float* __restrict__ Whh0,
  const float* __restrict__ bih0, const float* __restrict__ bhh0,
  const float* __restrict__ Wih0r,const float* __restrict__ Whh0r,
  const float* __restrict__ bih0r,const float* __restrict__ bhh0r,
  const float* __restrict__ Wih1, const float* __restrict__ Whh1,
  const float* __restrict__ bih1, const float* __restrict__ bhh1,
  const float* __restrict__ Wih1r,const float* __restrict__ bih1r,
  const float* __restrict__ bhh1r,
  const float* __restrict__ fc1w, const float* __restrict__ fc1b,
  const float* __restrict__ gma,  const float* __restrict__ bta,
  const float* __restrict__ mean, const float* __restrict__ var,
  const float* __restrict__ fc2w, const float* __restrict__ fc2b,
  us* __restrict__ wcat0, us* __restrict__ wcat1, us* __restrict__ w1r,
  us* __restrict__ fc1wb, us* __restrict__ fc2wp,
  float* __restrict__ brz0, float* __restrict__ bnih0, float* __restrict__ bnhh0,
  float* __restrict__ brz1, float* __restrict__ bnih1, float* __restrict__ bnhh1,
  float* __restrict__ brz1r,float* __restrict__ bnih1r,float* __restrict__ bnhh1r,
  float* __restrict__ sc2,  float* __restrict__ sh2,   float* __restrict__ fc2bp)
{
  const int tid = blockIdx.x * blockDim.x + threadIdx.x;
  const int np  = gridDim.x * blockDim.x;
  // layer-0 fused: [dir][1536][640]; 0..27 W_ih, 28..31 pad, 32..543 W_hh, 544..639 pad
  for (int i = tid; i < 2*1536*640; i += np){
    int d = i / (1536*640); int rem = i - d*(1536*640);
    int n = rem / 640, k = rem - n*640;
    const float* ih = d ? Wih0r : Wih0;
    const float* hh = d ? Whh0r : Whh0;
    float v = (k < 32) ? (k < 28 ? ih[n*28 + k] : 0.f)
                       : (k < 544 ? hh[n*512 + (k-32)] : 0.f);
    wcat0[i] = f2bf(v);
  }
  for (int i = tid; i < 1536*1536; i += np){
    int n = i / 1536, k = i - n*1536;
    float v = (k < 1024) ? Wih1[n*1024 + k] : Whh1[n*512 + (k-1024)];
    wcat1[i] = f2bf(v);
  }
  for (int i = tid; i < 1536*1024; i += np) w1r[i]   = f2bf(Wih1r[i]);
  for (int i = tid; i < 256*1024;  i += np) fc1wb[i] = f2bf(fc1w[i]);
  for (int i = tid; i < 16*256;    i += np){
    int n = i / 256; fc2wp[i] = (n < 10) ? f2bf(fc2w[i]) : (us)0;
  }
  for (int i = tid; i < 1024; i += np){
    brz0[i]        = bih0[i]  + bhh0[i];
    brz0[1024 + i] = bih0r[i] + bhh0r[i];
    brz1[i]        = bih1[i]  + bhh1[i];
    brz1r[i]       = bih1r[i] + bhh1r[i];
  }
  for (int i = tid; i < 512; i += np){
    bnih0[i]       = bih0[1024 + i];   bnhh0[i]       = bhh0[1024 + i];
    bnih0[512 + i] = bih0r[1024 + i];  bnhh0[512 + i] = bhh0r[1024 + i];
    bnih1[i]       = bih1[1024 + i];   bnhh1[i]       = bhh1[1024 + i];
    bnih1r[i]      = bih1r[1024 + i];  bnhh1r[i]      = bhh1r[1024 + i];
  }
  for (int i = tid; i < 256; i += np){
    float s = gma[i] * rsqrtf(var[i] + 1e-5f);
    sc2[i] = s;
    sh2[i] = (fc1b[i] - mean[i]) * s + bta[i];
  }
  for (int i = tid; i < 16; i += np) fc2bp[i] = (i < 10) ? fc2b[i] : 0.f;
}

// ---------------- generic GRU step ----------------
// One recurrent step as a 2D-tiled GEMM + gate epilogue.
// grid 512: hcb = bid&7 (64 h-cols; with round-robin block->XCD this makes the
// 590 KB W-slice XCD-L2-resident), nm = bid>>3 (M tile of 64).
// 8 waves: wm = w>>2 (32 M rows), wn = w&3 (16 hc).
// A = [seg0 (K0, fp32-x if xf32) | seg1 (K1) | h (512) | zero-pad]; K = nk*32,
// nk MULTIPLE OF 4 (K mult of 128; W zero-padded accordingly).
// Latency fix vs r6 (4500 cyc/barrier-interval measured): 4 chunks (128 K) per
// barrier interval -> 12/5/8 intervals instead of 48/20/32; A staged one FULL
// interval ahead (2 uint4/thread); B prefetch distance 2 chunks via 4 rotating
// register triples with LITERAL indices only (r4 spill bug avoided).
__global__ __launch_bounds__(512) void gru_step_kernel(
  const float* __restrict__ xf32, long xstride,
  const us* __restrict__ src0, long s0stride, int K0,
  const us* __restrict__ src1, long s1stride, int K1,
  const us* __restrict__ hIn, float* __restrict__ hF, us* __restrict__ hOut,
  us* __restrict__ y, long ystride,
  const us* __restrict__ W, int Kw, int nk, int kxn, int first,
  const float* __restrict__ brz, const float* __restrict__ bni,
  const float* __restrict__ bnh)
{
  // 2 interval-buffers x 4 chunk-slabs x [64 rows][32 cols pad->40]
  __shared__ us As[2*4*2560];

  const int tid = threadIdx.x, bid = blockIdx.x;
  const int hcb = bid & 7, nm = bid >> 3;
  const size_t Mbase = (size_t)nm * 64;
  const int hcBase = hcb * 64;
  const int K01 = K0 + K1;
  const int nki = nk >> 2;

  const int w = tid >> 6, lane = tid & 63, ln = lane & 15, lq = lane >> 4;
  const int wm = w >> 2, wn = w & 3;
  // staging: thread stages 2 slots: chunk-in-interval (2*sc+j), row srow, grp sgrp
  const int sc = tid >> 8, srow = (tid & 255) >> 2, sgrp = tid & 3;
  const size_t mrow = Mbase + srow;

  const us* pB0 = W + (size_t)(       hcBase + wn*16 + ln) * Kw + lq*8;
  const us* pB1 = W + (size_t)( 512 + hcBase + wn*16 + ln) * Kw + lq*8;
  const us* pB2 = W + (size_t)(1024 + hcBase + wn*16 + ln) * Kw + lq*8;

  auto loadA = [&](int c) -> uint4 {   // c = global 32-col chunk index
    const int col = c*32 + sgrp*8;
    if (col < K0){
      if (xf32){
        const float* xr = xf32 + mrow*xstride;
        us t8[8];
        #pragma unroll
        for (int j = 0; j < 8; ++j){
          int cc = col + j;
          t8[j] = (cc < 28) ? f2bf(xr[cc]) : (us)0;
        }
        return *reinterpret_cast<uint4*>(t8);
      }
      return *reinterpret_cast<const uint4*>(src0 + mrow*s0stride + col);
    }
    if (col < K01)
      return *reinterpret_cast<const uint4*>(src1 + mrow*s1stride + (col - K0));
    if (col < K01 + 512 && !first)
      return *reinterpret_cast<const uint4*>(hIn + mrow*512 + (col - K01));
    return uint4{0,0,0,0};
  };
  auto stA = [&](int buf, int ci, uint4 v){   // ci = chunk-in-interval (0..3)
    *reinterpret_cast<uint4*>(&As[buf*10240 + ci*2560 + srow*40 + sgrp*8]) = v;
  };

  // ---- prologue: interval 0 -> LDS; interval 1 -> regs; B chunks 0,1 -> regs
  {
    uint4 p0 = loadA(2*sc), p1 = loadA(2*sc + 1);
    stA(0, 2*sc, p0); stA(0, 2*sc + 1, p1);
  }
  uint4 svA = loadA(4 + 2*sc), svB = loadA(4 + 2*sc + 1);
  bf8 Tr[4], Tz[4], Tn[4];
  Tr[0] = ldb(pB0);      Tz[0] = ldb(pB1);      Tn[0] = ldb(pB2);
  Tr[1] = ldb(pB0 + 32); Tz[1] = ldb(pB1 + 32); Tn[1] = ldb(pB2 + 32);
  __syncthreads();

  f4 accR[2] = {}, accZ[2] = {}, accN[2] = {}, accXN[2] = {};

  for (int ki = 0; ki < nki; ++ki){
    const int base = (ki & 1) * 10240;
    const int kt0 = ki * 4;
    // ---- chunk c=0 (consume Tr[0], prefetch chunk kt0+2 -> slot 2)
    {
      if (kt0 + 2 < nk){
        const int kc = (kt0 + 2) * 32;
        Tr[2] = ldb(pB0 + kc); Tz[2] = ldb(pB1 + kc); Tn[2] = ldb(pB2 + kc);
      }
      bf8 a0 = ldb(&As[base + 0*2560 + (wm*32 +  0 + ln)*40 + lq*8]);
      bf8 a1 = ldb(&As[base + 0*2560 + (wm*32 + 16 + ln)*40 + lq*8]);
      accR[0] = mfma(a0, Tr[0], accR[0]); accR[1] = mfma(a1, Tr[0], accR[1]);
      accZ[0] = mfma(a0, Tz[0], accZ[0]); accZ[1] = mfma(a1, Tz[0], accZ[1]);
      accN[0] = mfma(a0, Tn[0], accN[0]); accN[1] = mfma(a1, Tn[0], accN[1]);
      if (kt0 == kxn - 1){
        accXN[0] = accN[0]; accXN[1] = accN[1];
        accN[0] = f4{0.f,0.f,0.f,0.f}; accN[1] = f4{0.f,0.f,0.f,0.f};
      }
    }
    // ---- chunk c=1 (consume slot 1, prefetch kt0+3 -> slot 3)
    {
      if (kt0 + 3 < nk){
        const int kc = (kt0 + 3) * 32;
        Tr[3] = ldb(pB0 + kc); Tz[3] = ldb(pB1 + kc); Tn[3] = ldb(pB2 + kc);
      }
      bf8 a0 = ldb(&As[base + 1*2560 + (wm*32 +  0 + ln)*40 + lq*8]);
      bf8 a1 = ldb(&As[base + 1*2560 + (wm*32 + 16 + ln)*40 + lq*8]);
      accR[0] = mfma(a0, Tr[1], accR[0]); accR[1] = mfma(a1, Tr[1], accR[1]);
      accZ[0] = mfma(a0, Tz[1], accZ[0]); accZ[1] = mfma(a1, Tz[1], accZ[1]);
      accN[0] = mfma(a0, Tn[1], accN[0]); accN[1] = mfma(a1, Tn[1], accN[1]);
      if (kt0 + 1 == kxn - 1){
        accXN[0] = accN[0]; accXN[1] = accN[1];
        accN[0] = f4{0.f,0.f,0.f,0.f}; accN[1] = f4{0.f,0.f,0.f,0.f};
      }
    }
    // ---- chunk c=2 (consume slot 2, prefetch kt0+4 -> slot 0)
    {
      if (kt0 + 4 < nk){
        const int kc = (kt0 + 4) * 32;
        Tr[0] = ldb(pB0 + kc); Tz[0] = ldb(pB1 + kc); Tn[0] = ldb(pB2 + kc);
      }
      bf8 a0 = ldb(&As[base + 2*2560 + (wm*32 +  0 + ln)*40 + lq*8]);
      bf8 a1 = ldb(&As[base + 2*2560 + (wm*32 + 16 + ln)*40 + lq*8]);
      accR[0] = mfma(a0, Tr[2], accR[0]); accR[1] = mfma(a1, Tr[2], accR[1]);
      accZ[0] = mfma(a0, Tz[2], accZ[0]); accZ[1] = mfma(a1, Tz[2], accZ[1]);
      accN[0] = mfma(a0, Tn[2], accN[0]); accN[1] = mfma(a1, Tn[2], accN[1]);
      if (kt0 + 2 == kxn - 1){
        accXN[0] = accN[0]; accXN[1] = accN[1];
        accN[0] = f4{0.f,0.f,0.f,0.f}; accN[1] = f4{0.f,0.f,0.f,0.f};
      }
    }
    // ---- chunk c=3 (consume slot 3, prefetch kt0+5 -> slot 1)
    {
      if (kt0 + 5 < nk){
        const int kc = (kt0 + 5) * 32;
        Tr[1] = ldb(pB0 + kc); Tz[1] = ldb(pB1 + kc); Tn[1] = ldb(pB2 + kc);
      }
      bf8 a0 = ldb(&As[base + 3*2560 + (wm*32 +  0 + ln)*40 + lq*8]);
      bf8 a1 = ldb(&As[base + 3*2560 + (wm*32 + 16 + ln)*40 + lq*8]);
      accR[0] = mfma(a0, Tr[3], accR[0]); accR[1] = mfma(a1, Tr[3], accR[1]);
      accZ[0] = mfma(a0, Tz[3], accZ[0]); accZ[1] = mfma(a1, Tz[3], accZ[1]);
      accN[0] = mfma(a0, Tn[3], accN[0]); accN[1] = mfma(a1, Tn[3], accN[1]);
      if (kt0 + 3 == kxn - 1){
        accXN[0] = accN[0]; accXN[1] = accN[1];
        accN[0] = f4{0.f,0.f,0.f,0.f}; accN[1] = f4{0.f,0.f,0.f,0.f};
      }
    }
    // ---- stage next interval (data loaded one interval ago), start interval+2 loads
    if (ki + 1 < nki){
      const int nbuf = (ki + 1) & 1;
      stA(nbuf, 2*sc, svA); stA(nbuf, 2*sc + 1, svB);
      if (ki + 2 < nki){
        svA = loadA((ki + 2)*4 + 2*sc);
        svB = loadA((ki + 2)*4 + 2*sc + 1);
      }
      __syncthreads();
    }
  }

  // ---- gate epilogue ----
  const int c = hcBase + wn*16 + ln;
  const float br = brz[c], bz = brz[512 + c], bi = bni[c], bh = bnh[c];
  #pragma unroll
  for (int mt = 0; mt < 2; ++mt){
    #pragma unroll
    for (int e = 0; e < 4; ++e){
      const size_t m = Mbase + wm*32 + mt*16 + lq*4 + e;
      float r = sigm(accR[mt][e] + br);
      float z = sigm(accZ[mt][e] + bz);
      float n = tanhf(accXN[mt][e] + bi + r*(accN[mt][e] + bh));
      float hprev = first ? 0.f : hF[m*512 + c];
      float h = (1.f - z)*n + z*hprev;
      hF[m*512 + c] = h;
      us hb = f2bf(h);
      hOut[m*512 + c] = hb;
      if (y) y[m*ystride + c] = hb;
    }
  }
}

// ---------------- head: [h1f|h1b] -> fc1 -> bn/relu -> fc2 -> log_softmax ----
__global__ __launch_bounds__(512) void head_kernel(
  const us* __restrict__ h1f, const us* __restrict__ h1b,
  const us* __restrict__ fc1w, const us* __restrict__ fc2wp,
  const float* __restrict__ sc2, const float* __restrict__ sh2,
  const float* __restrict__ fc2b, float* __restrict__ out)
{
  constexpr int APS = 1048;
  __shared__ us As[32 * APS];
  __shared__ us actS[32 * 264];
  __shared__ float lg[32 * 16];
  const int tid = threadIdx.x;
  const size_t row0 = (size_t)blockIdx.x * 32;
  const int w = tid >> 6, lane = tid & 63, ln = lane & 15, lq = lane >> 4;

  for (int i = tid; i < 32*128; i += 512){
    int r = i >> 7, g = i & 127, col = g*8;
    uint4 v = (col < 512)
      ? *reinterpret_cast<const uint4*>(h1f + (row0 + r)*512 + col)
      : *reinterpret_cast<const uint4*>(h1b + (row0 + r)*512 + (col - 512));
    *reinterpret_cast<uint4*>(&As[r*APS + col]) = v;
  }
  __syncthreads();

  {
    f4 acc[2][2] = {};
    for (int kt = 0; kt < 32; ++kt){
      const int kc = kt*32 + lq*8;
      bf8 a0 = ldb(&As[ln*APS + kc]);
      bf8 a1 = ldb(&As[(16 + ln)*APS + kc]);
      #pragma unroll
      for (int nt = 0; nt < 2; ++nt){
        const int col = w*32 + nt*16 + ln;
        bf8 b = ldb(&fc1w[(size_t)col*1024 + kc]);
        acc[0][nt] = mfma(a0, b, acc[0][nt]);
        acc[1][nt] = mfma(a1, b, acc[1][nt]);
      }
    }
    #pragma unroll
    for (int nt = 0; nt < 2; ++nt){
      const int col = w*32 + nt*16 + ln;
      const float sc = sc2[col], sh = sh2[col];
      #pragma unroll
      for (int mt = 0; mt < 2; ++mt)
        #pragma unroll
        for (int e = 0; e < 4; ++e){
          float v = fmaxf(acc[mt][nt][e]*sc + sh, 0.f);
          actS[(mt*16 + lq*4 + e)*264 + col] = f2bf(v);
        }
    }
    __syncthreads();
  }

  if (w == 0){
    f4 acc[2] = {};
    for (int kt = 0; kt < 8; ++kt){
      const int kc = kt*32 + lq*8;
      bf8 a0 = ldb(&actS[ln*264 + kc]);
      bf8 a1 = ldb(&actS[(16 + ln)*264 + kc]);
      bf8 b  = ldb(&fc2wp[ln*256 + kc]);
      acc[0] = mfma(a0, b, acc[0]);
      acc[1] = mfma(a1, b, acc[1]);
    }
    const float bb = fc2b[ln];
    #pragma unroll
    for (int mt = 0; mt < 2; ++mt)
      #pragma unroll
      for (int e = 0; e < 4; ++e)
        lg[(mt*16 + lq*4 + e)*16 + ln] = acc[mt][e] + bb;
  }
  __syncthreads();
  if (tid < 32){
    const int r = tid;
    float mx = -1e30f;
    for (int cc = 0; cc < 10; ++cc) mx = fmaxf(mx, lg[r*16 + cc]);
    float sum = 0.f;
    for (int cc = 0; cc < 10; ++cc) sum += __expf(lg[r*16 + cc] - mx);
    const float lse = mx + logf(sum);
    for (int cc = 0; cc < 10; ++cc)
      out[(row0 + r)*10 + cc] = lg[r*16 + cc] - lse;
  }
}

// ---------------- launch ----------------
extern "C" void kernel_launch(void* const* d_in, const int* in_sizes, int n_in,
                              void* d_out, int out_size, void* d_ws, size_t ws_size,
                              hipStream_t stream)
{
  (void)in_sizes; (void)n_in; (void)out_size; (void)ws_size;
  char* ws = (char*)d_ws;
  auto US = [&](size_t off){ return (us*)(ws + off); };
  auto FP = [&](size_t off){ return (float*)(ws + off); };

  const float* x      = (const float*)d_in[0];
  const float* Wih0   = (const float*)d_in[1];
  const float* Whh0   = (const float*)d_in[2];
  const float* bih0   = (const float*)d_in[3];
  const float* bhh0   = (const float*)d_in[4];
  const float* Wih0r  = (const float*)d_in[5];
  const float* Whh0r  = (const float*)d_in[6];
  const float* bih0r  = (const float*)d_in[7];
  const float* bhh0r  = (const float*)d_in[8];
  const float* Wih1   = (const float*)d_in[9];
  const float* Whh1   = (const float*)d_in[10];
  const float* bih1   = (const float*)d_in[11];
  const float* bhh1   = (const float*)d_in[12];
  const float* Wih1r  = (const float*)d_in[13];
  // d_in[14] (W_hh_l1r) unused: backward layer-1 runs exactly one step from h=0.
  const float* bih1r  = (const float*)d_in[15];
  const float* bhh1r  = (const float*)d_in[16];
  const float* fc1w   = (const float*)d_in[17];
  const float* fc1b   = (const float*)d_in[18];
  const float* gma    = (const float*)d_in[19];
  const float* bta    = (const float*)d_in[20];
  const float* mean   = (const float*)d_in[21];
  const float* var    = (const float*)d_in[22];
  const float* fc2w   = (const float*)d_in[23];
  const float* fc2b   = (const float*)d_in[24];

  prep_kernel<<<512, 256, 0, stream>>>(
    Wih0, Whh0, bih0, bhh0, Wih0r, Whh0r, bih0r, bhh0r,
    Wih1, Whh1, bih1, bhh1, Wih1r, bih1r, bhh1r,
    fc1w, fc1b, gma, bta, mean, var, fc2w, fc2b,
    US(OFF_WCAT0), US(OFF_WCAT1), US(OFF_W1R), US(OFF_FC1W), US(OFF_FC2W),
    FP(OFF_BRZ0), FP(OFF_BNIH0), FP(OFF_BNHH0),
    FP(OFF_BRZ1), FP(OFF_BNIH1), FP(OFF_BNHH1),
    FP(OFF_BRZ1R), FP(OFF_BNIH1R), FP(OFF_BNHH1R),
    FP(OFF_SC2), FP(OFF_SH2), FP(OFF_FC2B));

  us* y0b  = US(OFF_Y0B);
  us* h0bf = US(OFF_H0BF);
  us* h1bf = US(OFF_H1BF);

  // ---- phase A: layer-0 backward (materialize y0b) ----
  for (int s = 0; s < 28; ++s){
    const int t = 27 - s;
    gru_step_kernel<<<512, 512, 0, stream>>>(
      x + t*28, 784, nullptr, 0, 32, nullptr, 0, 0,
      h0bf + (s & 1)*PP, FP(OFF_H0F32), h0bf + ((s & 1) ^ 1)*PP,
      y0b + t*512, 28ll*512,
      US(OFF_WCAT0) + 1536ll*640, 640, 20, 1, s == 0,
      FP(OFF_BRZ0) + 1024, FP(OFF_BNIH0) + 512, FP(OFF_BNHH0) + 512);
  }

  // ---- phase B: layer-0 forward + layer-1 forward interleaved ----
  for (int s = 0; s < 28; ++s){
    gru_step_kernel<<<512, 512, 0, stream>>>(
      x + s*28, 784, nullptr, 0, 32, nullptr, 0, 0,
      h0bf + (s & 1)*PP, FP(OFF_H0F32), h0bf + ((s & 1) ^ 1)*PP,
      nullptr, 0,
      US(OFF_WCAT0), 640, 20, 1, s == 0,
      FP(OFF_BRZ0), FP(OFF_BNIH0), FP(OFF_BNHH0));

    gru_step_kernel<<<512, 512, 0, stream>>>(
      nullptr, 0,
      h0bf + ((s & 1) ^ 1)*PP, 512, 512,      // y0f slice = h0f output of this step
      y0b + s*512, 28ll*512, 512,             // y0b slice
      h1bf + (s & 1)*PP, FP(OFF_H1F32), h1bf + ((s & 1) ^ 1)*PP,
      nullptr, 0,
      US(OFF_WCAT1), 1536, 48, 32, s == 0,
      FP(OFF_BRZ1), FP(OFF_BNIH1), FP(OFF_BNHH1));
  }

  // ---- layer-1 backward: single step from h=0 on [y0f(27)|y0b(27)] ----
  gru_step_kernel<<<512, 512, 0, stream>>>(
    nullptr, 0,
    h0bf + 0*PP, 512, 512,                    // y0f t=27 (l0f(27) wrote pp buffer 0)
    y0b + 27*512, 28ll*512, 512,
    h1bf, FP(OFF_H1F32), US(OFF_H1BBF),
    nullptr, 0,
    US(OFF_W1R), 1024, 32, 32, 1,
    FP(OFF_BRZ1R), FP(OFF_BNIH1R), FP(OFF_BNHH1R));

  // ---- head (final h1f is pp buffer 0 after 28 steps) ----
  head_kernel<<<128, 512, 0, stream>>>(
    h1bf, US(OFF_H1BBF), US(OFF_FC1W), US(OFF_FC2W),
    FP(OFF_SC2), FP(OFF_SH2), FP(OFF_FC2B), (float*)d_out);
}

// Round 8
// 3252.994 us; speedup vs baseline: 1.5796x; 1.5796x over previous
//
#include <hip/hip_runtime.h>

#define DEV __device__ __forceinline__
typedef unsigned short us;
typedef __bf16 bf8 __attribute__((ext_vector_type(8)));
typedef float  f4  __attribute__((ext_vector_type(4)));

DEV us f2bf(float f){
  unsigned int u = __builtin_bit_cast(unsigned int, f);
  u = u + 0x7fffu + ((u >> 16) & 1u);
  return (us)(u >> 16);
}
DEV float bf2f(us u){ unsigned int v = ((unsigned int)u) << 16; return __builtin_bit_cast(float, v); }
DEV float sigm(float x){ return 1.f/(1.f + __expf(-x)); }
DEV bf8 ldb(const us* p){ return *reinterpret_cast<const bf8*>(p); }
DEV f4 mfma(bf8 a, bf8 b, f4 c){ return __builtin_amdgcn_mfma_f32_16x16x32_bf16(a, b, c, 0, 0, 0); }

// ---------------- workspace layout (bytes) — total ~234 MB (<246.75 proven safe)
constexpr size_t OFF_WHH0F  = 0;                             // [1536][512] bf16
constexpr size_t OFF_WHH0R  = OFF_WHH0F + 1536ull*512*2;
constexpr size_t OFF_WIH0F  = OFF_WHH0R + 1536ull*512*2;     // [1536][32] bf16
constexpr size_t OFF_WIH0R  = OFF_WIH0F + 1536ull*32*2;
constexpr size_t OFF_WIH1   = OFF_WIH0R + 1536ull*32*2;      // [1536][1024] bf16
constexpr size_t OFF_WHH1   = OFF_WIH1  + 1536ull*1024*2;    // [1536][512] bf16
constexpr size_t OFF_WIH1R  = OFF_WHH1  + 1536ull*512*2;     // [1536][1024] bf16
constexpr size_t OFF_FC1W   = OFF_WIH1R + 1536ull*1024*2;    // [256][1024] bf16
constexpr size_t OFF_FC2W   = OFF_FC1W  + 256ull*1024*2;     // [16][256] bf16
constexpr size_t OFF_BRZ0   = OFF_FC2W  + 16ull*256*2;       // [2][1024] f32
constexpr size_t OFF_BNIH0  = OFF_BRZ0  + 2*1024*4;          // [2][512]
constexpr size_t OFF_BNHH0  = OFF_BNIH0 + 2*512*4;           // [2][512]
constexpr size_t OFF_BRZ1   = OFF_BNHH0 + 2*512*4;           // [1024]
constexpr size_t OFF_BNIH1  = OFF_BRZ1  + 1024*4;            // [512]
constexpr size_t OFF_BNHH1  = OFF_BNIH1 + 512*4;             // [512]
constexpr size_t OFF_BRZ1R  = OFF_BNHH1 + 512*4;             // [1024]
constexpr size_t OFF_BNIH1R = OFF_BRZ1R + 1024*4;            // [512]
constexpr size_t OFF_BNHH1R = OFF_BNIH1R+ 512*4;             // [512]
constexpr size_t OFF_SC2    = OFF_BNHH1R+ 512*4;             // [256]
constexpr size_t OFF_SH2    = OFF_SC2   + 256*4;             // [256]
constexpr size_t OFF_FC2B   = OFF_SH2   + 256*4;             // [16]
constexpr size_t OFF_Y0B    = OFF_FC2B  + 64;                // [4096][28][512] bf16
constexpr size_t OFF_Y0FC   = OFF_Y0B   + 4096ull*28*512*2;  // [4096][4][512] bf16 (chunk)
constexpr size_t OFF_GX     = OFF_Y0FC  + 4096ull*4*512*2;   // [4][4096][1536] bf16
constexpr size_t OFF_H0BF   = OFF_GX    + 4ull*4096*1536*2;  // [2pp][4096][512] bf16
constexpr size_t OFF_H0F32  = OFF_H0BF  + 2ull*4096*512*2;   // [4096][512] f32
constexpr size_t OFF_H1BF   = OFF_H0F32 + 4096ull*512*4;     // [2pp][4096][512] bf16
constexpr size_t OFF_H1F32  = OFF_H1BF  + 2ull*4096*512*2;   // [4096][512] f32
constexpr size_t OFF_H1B    = OFF_H1F32 + 4096ull*512*4;     // [4096][512] bf16

constexpr long PPH   = 4096ll*512;     // h ping-pong plane (elems)
constexpr long PLANE = 4096ll*1536;    // gx per-t plane (elems)

// ---------------- K0: weight/bias prep ----------------
__global__ void prep_kernel(
  const float* __restrict__ Wih0, const float* __restrict__ Whh0,
  const float* __restrict__ bih0, const float* __restrict__ bhh0,
  const float* __restrict__ Wih0r,const float* __restrict__ Whh0r,
  const float* __restrict__ bih0r,const float* __restrict__ bhh0r,
  const float* __restrict__ Wih1, const float* __restrict__ Whh1,
  const float* __restrict__ bih1, const float* __restrict__ bhh1,
  const float* __restrict__ Wih1r,const float* __restrict__ bih1r,
  const float* __restrict__ bhh1r,
  const float* __restrict__ fc1w, const float* __restrict__ fc1b,
  const float* __restrict__ gma,  const float* __restrict__ bta,
  const float* __restrict__ mean, const float* __restrict__ var,
  const float* __restrict__ fc2w, const float* __restrict__ fc2b,
  us* __restrict__ whh0f, us* __restrict__ whh0r,
  us* __restrict__ wih0f, us* __restrict__ wih0r,
  us* __restrict__ wih1,  us* __restrict__ whh1, us* __restrict__ wih1r,
  us* __restrict__ fc1wb, us* __restrict__ fc2wp,
  float* __restrict__ brz0, float* __restrict__ bnih0, float* __restrict__ bnhh0,
  float* __restrict__ brz1, float* __restrict__ bnih1, float* __restrict__ bnhh1,
  float* __restrict__ brz1r,float* __restrict__ bnih1r,float* __restrict__ bnhh1r,
  float* __restrict__ sc2,  float* __restrict__ sh2,   float* __restrict__ fc2bp)
{
  const int tid = blockIdx.x * blockDim.x + threadIdx.x;
  const int np  = gridDim.x * blockDim.x;
  for (int i = tid; i < 1536*512; i += np){
    whh0f[i] = f2bf(Whh0[i]);
    whh0r[i] = f2bf(Whh0r[i]);
    whh1[i]  = f2bf(Whh1[i]);
  }
  for (int i = tid; i < 1536*32; i += np){
    int n = i >> 5, k = i & 31;
    wih0f[i] = (k < 28) ? f2bf(Wih0[n*28 + k])  : (us)0;
    wih0r[i] = (k < 28) ? f2bf(Wih0r[n*28 + k]) : (us)0;
  }
  for (int i = tid; i < 1536*1024; i += np){
    wih1[i]  = f2bf(Wih1[i]);
    wih1r[i] = f2bf(Wih1r[i]);
  }
  for (int i = tid; i < 256*1024; i += np) fc1wb[i] = f2bf(fc1w[i]);
  for (int i = tid; i < 16*256;   i += np){
    int n = i / 256; fc2wp[i] = (n < 10) ? f2bf(fc2w[i]) : (us)0;
  }
  for (int i = tid; i < 1024; i += np){
    brz0[i]        = bih0[i]  + bhh0[i];
    brz0[1024 + i] = bih0r[i] + bhh0r[i];
    brz1[i]        = bih1[i]  + bhh1[i];
    brz1r[i]       = bih1r[i] + bhh1r[i];
  }
  for (int i = tid; i < 512; i += np){
    bnih0[i]       = bih0[1024 + i];   bnhh0[i]       = bhh0[1024 + i];
    bnih0[512 + i] = bih0r[1024 + i];  bnhh0[512 + i] = bhh0r[1024 + i];
    bnih1[i]       = bih1[1024 + i];   bnhh1[i]       = bhh1[1024 + i];
    bnih1r[i]      = bih1r[1024 + i];  bnhh1r[i]      = bhh1r[1024 + i];
  }
  for (int i = tid; i < 256; i += np){
    float s = gma[i] * rsqrtf(var[i] + 1e-5f);
    sc2[i] = s;
    sh2[i] = (fc1b[i] - mean[i]) * s + bta[i];
  }
  for (int i = tid; i < 16; i += np) fc2bp[i] = (i < 10) ? fc2b[i] : 0.f;
}

// ---------------- big GEMM: C[sl][m][1536] = A @ B^T (bf16, no bias) ----------------
// A row R: m = R>>tshift, sl = R & ((1<<tshift)-1).
//   if xf32: row = xf32 + m*784 + sl*xt (f32, 28 cols + pad to 32), K0=32
//   else: seg0 = s0 + m*s0m + sl*s0t (K0 cols); seg1 = s1 + m*s1m + sl*s1t (K1 cols)
// B: [1536][Kw]. Block tile 128M x 128N; grid = nMtiles * 12; mtile = bid % nMtiles
// (nMtiles % 8 == 0 -> all N-blocks of one mtile co-XCD -> A fetched once per XCD).
__global__ __launch_bounds__(512) void gemm_kernel(
  const float* __restrict__ xf32, long xt,
  const us* __restrict__ s0, long s0m, long s0t, int K0,
  const us* __restrict__ s1, long s1m, long s1t, int K1,
  const us* __restrict__ B, int Kw, int nk, int tshift, int nMtiles,
  us* __restrict__ C, long cT)
{
  __shared__ us As[2*128*40];

  const int tid = threadIdx.x, bid = blockIdx.x;
  const int mtile = bid % nMtiles, ntile = bid / nMtiles;
  const int Mbase = mtile * 128, Nbase = ntile * 128;
  const int K01 = K0 + K1;
  const int mask = (1 << tshift) - 1;

  const int w = tid >> 6, lane = tid & 63, ln = lane & 15, lq = lane >> 4;
  const int wm = w >> 2, wn = w & 3;
  const int srow = tid >> 2, sgrp = tid & 3;

  const us* pB0 = B + (size_t)(Nbase + wn*32 +  0 + ln) * Kw + lq*8;
  const us* pB1 = B + (size_t)(Nbase + wn*32 + 16 + ln) * Kw + lq*8;

  auto loadA = [&](int kt) -> uint4 {
    const int R = Mbase + srow;
    const int m = R >> tshift, sl = R & mask;
    const int col = kt*32 + sgrp*8;
    if (xf32){
      const float* xr = xf32 + (size_t)m*784 + (long)sl*xt;
      us t8[8];
      #pragma unroll
      for (int j = 0; j < 8; ++j){
        int cc = col + j;
        t8[j] = (cc < 28) ? f2bf(xr[cc]) : (us)0;
      }
      return *reinterpret_cast<uint4*>(t8);
    }
    if (col < K0)
      return *reinterpret_cast<const uint4*>(s0 + (size_t)m*s0m + (long)sl*s0t + col);
    return *reinterpret_cast<const uint4*>(s1 + (size_t)m*s1m + (long)sl*s1t + (col - K0));
  };
  auto stA = [&](int buf, uint4 v){
    *reinterpret_cast<uint4*>(&As[buf + srow*40 + sgrp*8]) = v;
  };

  stA(0, loadA(0));
  bf8 b0 = ldb(pB0), b1 = ldb(pB1);
  __syncthreads();

  f4 acc[4][2] = {};

  for (int kt = 0; kt < nk; ++kt){
    const int buf = (kt & 1) * 5120;
    const bool more = (kt + 1) < nk;
    bf8 n0, n1; uint4 nv;
    if (more){
      const int kc = (kt + 1) * 32;
      n0 = ldb(pB0 + kc); n1 = ldb(pB1 + kc);
      nv = loadA(kt + 1);
    }
    bf8 a0 = ldb(&As[buf + (wm*64 +  0 + ln)*40 + lq*8]);
    bf8 a1 = ldb(&As[buf + (wm*64 + 16 + ln)*40 + lq*8]);
    bf8 a2 = ldb(&As[buf + (wm*64 + 32 + ln)*40 + lq*8]);
    bf8 a3 = ldb(&As[buf + (wm*64 + 48 + ln)*40 + lq*8]);
    acc[0][0] = mfma(a0, b0, acc[0][0]); acc[0][1] = mfma(a0, b1, acc[0][1]);
    acc[1][0] = mfma(a1, b0, acc[1][0]); acc[1][1] = mfma(a1, b1, acc[1][1]);
    acc[2][0] = mfma(a2, b0, acc[2][0]); acc[2][1] = mfma(a2, b1, acc[2][1]);
    acc[3][0] = mfma(a3, b0, acc[3][0]); acc[3][1] = mfma(a3, b1, acc[3][1]);
    if (more){
      stA(buf ^ 5120, nv);
      __syncthreads();
      b0 = n0; b1 = n1;
    }
  }

  #pragma unroll
  for (int mtf = 0; mtf < 4; ++mtf){
    #pragma unroll
    for (int ntf = 0; ntf < 2; ++ntf){
      const int col = Nbase + wn*32 + ntf*16 + ln;
      #pragma unroll
      for (int e = 0; e < 4; ++e){
        const int R = Mbase + wm*64 + mtf*16 + lq*4 + e;
        const int m = R >> tshift, sl = R & mask;
        C[(size_t)sl*cT + (size_t)m*1536 + col] = f2bf(acc[mtf][ntf][e]);
      }
    }
  }
}

// ---------------- serial GRU step: h' from gx + h @ Whh^T, W pinned in LDS ----
// K=512 fixed. grid 256 = 16 hcb(32 cols) x 16 nm(M=256); bid = hcb*16 + nm
// (co-XCD for same nm; Whh 1.57 MB stays L2-resident across steps per XCD).
// 8 waves: wave w = 32 M rows x full 96 N (3 gates x 32 cols).
__global__ __launch_bounds__(512) void gru_serial_kernel(
  const us* __restrict__ W, const us* __restrict__ gx,
  const us* __restrict__ hIn, float* __restrict__ hF, us* __restrict__ hOut,
  us* __restrict__ y, long ystride,
  const float* __restrict__ brz, const float* __restrict__ bni,
  const float* __restrict__ bnh, int first)
{
  __shared__ us Ws[96*520];       // W slab [96 rows][512 pad->520]
  __shared__ us As[2*256*40];     // A slabs [256 rows][32 pad->40], dbuf

  const int tid = threadIdx.x, bid = blockIdx.x;
  const int hcb = bid >> 4, nm = bid & 15;
  const size_t Mbase = (size_t)nm * 256;
  const int hcBase = hcb * 32;

  const int w = tid >> 6, lane = tid & 63, ln = lane & 15, lq = lane >> 4;

  f4 acc[3][2][2] = {};   // [gate][nt][mt]

  if (!first){
    // ---- load W slab (96 rows x 512) into LDS: 6144 uint4 / 512 thr = 12 each
    #pragma unroll
    for (int i = 0; i < 12; ++i){
      const int q = tid + i*512;
      const int rl = q >> 6, seg = q & 63;
      const int grow = (rl >> 5)*512 + hcBase + (rl & 31);
      *reinterpret_cast<uint4*>(&Ws[rl*520 + seg*8]) =
        *reinterpret_cast<const uint4*>(&W[(size_t)grow*512 + seg*8]);
    }
    // ---- A staging lambdas: slab = [256][32], 1024 uint4, 2 per thread
    auto ldA = [&](int kt, int q) -> uint4 {
      const int row = q >> 2, grp = q & 3;
      return *reinterpret_cast<const uint4*>(&hIn[(Mbase + row)*512 + kt*32 + grp*8]);
    };
    auto stA = [&](int buf, int q, uint4 v){
      const int row = q >> 2, grp = q & 3;
      *reinterpret_cast<uint4*>(&As[buf + row*40 + grp*8]) = v;
    };
    // prologue: slab0 -> LDS; slab1, slab2 -> regs (distance-2)
    stA(0, tid, ldA(0, tid)); stA(0, tid + 512, ldA(0, tid + 512));
    uint4 s1a = ldA(1, tid), s1b = ldA(1, tid + 512);
    uint4 s2a = ldA(2, tid), s2b = ldA(2, tid + 512);
    __syncthreads();

    for (int kt = 0; kt < 16; ++kt){
      const int buf = (kt & 1) * 10240;
      bf8 a0 = ldb(&As[buf + (w*32 +  0 + ln)*40 + lq*8]);
      bf8 a1 = ldb(&As[buf + (w*32 + 16 + ln)*40 + lq*8]);
      const int kc = kt*32 + lq*8;
      #pragma unroll
      for (int g = 0; g < 3; ++g){
        #pragma unroll
        for (int nt = 0; nt < 2; ++nt){
          bf8 b = ldb(&Ws[(g*32 + nt*16 + ln)*520 + kc]);
          acc[g][nt][0] = mfma(a0, b, acc[g][nt][0]);
          acc[g][nt][1] = mfma(a1, b, acc[g][nt][1]);
        }
      }
      if (kt < 15){
        stA(buf ^ 10240, tid, s1a); stA(buf ^ 10240, tid + 512, s1b);
        s1a = s2a; s1b = s2b;
        if (kt + 3 < 16){ s2a = ldA(kt + 3, tid); s2b = ldA(kt + 3, tid + 512); }
        __syncthreads();
      }
    }
  }

  // ---- gate epilogue: add gx (precomputed input projection) + biases
  #pragma unroll
  for (int nt = 0; nt < 2; ++nt){
    const int ch = hcBase + nt*16 + ln;
    const float br = brz[ch], bz = brz[512 + ch], bi = bni[ch], bh = bnh[ch];
    #pragma unroll
    for (int mt = 0; mt < 2; ++mt){
      #pragma unroll
      for (int e = 0; e < 4; ++e){
        const size_t m = Mbase + w*32 + mt*16 + lq*4 + e;
        const us* gxr = gx + m*1536;
        float r = sigm(acc[0][nt][mt][e] + bf2f(gxr[ch])        + br);
        float z = sigm(acc[1][nt][mt][e] + bf2f(gxr[512 + ch])  + bz);
        float n = tanhf(bf2f(gxr[1024 + ch]) + bi + r*(acc[2][nt][mt][e] + bh));
        float hprev = first ? 0.f : hF[m*512 + ch];
        float h = (1.f - z)*n + z*hprev;
        hF[m*512 + ch] = h;
        us hb = f2bf(h);
        hOut[m*512 + ch] = hb;
        if (y) y[m*ystride + ch] = hb;
      }
    }
  }
}

// ---------------- l1 backward single step: elementwise gates from gxb (h=0) ----
__global__ void gate1b_kernel(
  const us* __restrict__ gxb, const float* __restrict__ brz,
  const float* __restrict__ bni, const float* __restrict__ bnh,
  us* __restrict__ h1b)
{
  const int i = blockIdx.x * blockDim.x + threadIdx.x;
  if (i >= 4096*512) return;
  const int m = i >> 9, ch = i & 511;
  const us* g = gxb + (size_t)m*1536;
  float r = sigm(bf2f(g[ch]) + brz[ch]);
  float z = sigm(bf2f(g[512 + ch]) + brz[512 + ch]);
  float n = tanhf(bf2f(g[1024 + ch]) + bni[ch] + r*bnh[ch]);
  h1b[i] = f2bf((1.f - z)*n);
}

// ---------------- head: [h1f|h1b] -> fc1 -> bn/relu -> fc2 -> log_softmax ----
__global__ __launch_bounds__(512) void head_kernel(
  const us* __restrict__ h1f, const us* __restrict__ h1b,
  const us* __restrict__ fc1w, const us* __restrict__ fc2wp,
  const float* __restrict__ sc2, const float* __restrict__ sh2,
  const float* __restrict__ fc2b, float* __restrict__ out)
{
  constexpr int APS = 1048;
  __shared__ us As[32 * APS];
  __shared__ us actS[32 * 264];
  __shared__ float lg[32 * 16];
  const int tid = threadIdx.x;
  const size_t row0 = (size_t)blockIdx.x * 32;
  const int w = tid >> 6, lane = tid & 63, ln = lane & 15, lq = lane >> 4;

  for (int i = tid; i < 32*128; i += 512){
    int r = i >> 7, g = i & 127, col = g*8;
    uint4 v = (col < 512)
      ? *reinterpret_cast<const uint4*>(h1f + (row0 + r)*512 + col)
      : *reinterpret_cast<const uint4*>(h1b + (row0 + r)*512 + (col - 512));
    *reinterpret_cast<uint4*>(&As[r*APS + col]) = v;
  }
  __syncthreads();

  {
    f4 acc[2][2] = {};
    for (int kt = 0; kt < 32; ++kt){
      const int kc = kt*32 + lq*8;
      bf8 a0 = ldb(&As[ln*APS + kc]);
      bf8 a1 = ldb(&As[(16 + ln)*APS + kc]);
      #pragma unroll
      for (int nt = 0; nt < 2; ++nt){
        const int col = w*32 + nt*16 + ln;
        bf8 b = ldb(&fc1w[(size_t)col*1024 + kc]);
        acc[0][nt] = mfma(a0, b, acc[0][nt]);
        acc[1][nt] = mfma(a1, b, acc[1][nt]);
      }
    }
    #pragma unroll
    for (int nt = 0; nt < 2; ++nt){
      const int col = w*32 + nt*16 + ln;
      const float sc = sc2[col], sh = sh2[col];
      #pragma unroll
      for (int mt = 0; mt < 2; ++mt)
        #pragma unroll
        for (int e = 0; e < 4; ++e){
          float v = fmaxf(acc[mt][nt][e]*sc + sh, 0.f);
          actS[(mt*16 + lq*4 + e)*264 + col] = f2bf(v);
        }
    }
    __syncthreads();
  }

  if (w == 0){
    f4 acc[2] = {};
    for (int kt = 0; kt < 8; ++kt){
      const int kc = kt*32 + lq*8;
      bf8 a0 = ldb(&actS[ln*264 + kc]);
      bf8 a1 = ldb(&actS[(16 + ln)*264 + kc]);
      bf8 b  = ldb(&fc2wp[ln*256 + kc]);
      acc[0] = mfma(a0, b, acc[0]);
      acc[1] = mfma(a1, b, acc[1]);
    }
    const float bb = fc2b[ln];
    #pragma unroll
    for (int mt = 0; mt < 2; ++mt)
      #pragma unroll
      for (int e = 0; e < 4; ++e)
        lg[(mt*16 + lq*4 + e)*16 + ln] = acc[mt][e] + bb;
  }
  __syncthreads();
  if (tid < 32){
    const int r = tid;
    float mx = -1e30f;
    for (int cc = 0; cc < 10; ++cc) mx = fmaxf(mx, lg[r*16 + cc]);
    float sum = 0.f;
    for (int cc = 0; cc < 10; ++cc) sum += __expf(lg[r*16 + cc] - mx);
    const float lse = mx + logf(sum);
    for (int cc = 0; cc < 10; ++cc)
      out[(row0 + r)*10 + cc] = lg[r*16 + cc] - lse;
  }
}

// ---------------- launch ----------------
extern "C" void kernel_launch(void* const* d_in, const int* in_sizes, int n_in,
                              void* d_out, int out_size, void* d_ws, size_t ws_size,
                              hipStream_t stream)
{
  (void)in_sizes; (void)n_in; (void)out_size; (void)ws_size;
  char* ws = (char*)d_ws;
  auto US = [&](size_t off){ return (us*)(ws + off); };
  auto FP = [&](size_t off){ return (float*)(ws + off); };

  const float* x      = (const float*)d_in[0];
  const float* Wih0   = (const float*)d_in[1];
  const float* Whh0   = (const float*)d_in[2];
  const float* bih0   = (const float*)d_in[3];
  const float* bhh0   = (const float*)d_in[4];
  const float* Wih0r  = (const float*)d_in[5];
  const float* Whh0r  = (const float*)d_in[6];
  const float* bih0r  = (const float*)d_in[7];
  const float* bhh0r  = (const float*)d_in[8];
  const float* Wih1   = (const float*)d_in[9];
  const float* Whh1   = (const float*)d_in[10];
  const float* bih1   = (const float*)d_in[11];
  const float* bhh1   = (const float*)d_in[12];
  const float* Wih1r  = (const float*)d_in[13];
  // d_in[14] (W_hh_l1r) unused: backward layer-1 runs exactly one step from h=0.
  const float* bih1r  = (const float*)d_in[15];
  const float* bhh1r  = (const float*)d_in[16];
  const float* fc1w   = (const float*)d_in[17];
  const float* fc1b   = (const float*)d_in[18];
  const float* gma    = (const float*)d_in[19];
  const float* bta    = (const float*)d_in[20];
  const float* mean   = (const float*)d_in[21];
  const float* var    = (const float*)d_in[22];
  const float* fc2w   = (const float*)d_in[23];
  const float* fc2b   = (const float*)d_in[24];

  prep_kernel<<<512, 256, 0, stream>>>(
    Wih0, Whh0, bih0, bhh0, Wih0r, Whh0r, bih0r, bhh0r,
    Wih1, Whh1, bih1, bhh1, Wih1r, bih1r, bhh1r,
    fc1w, fc1b, gma, bta, mean, var, fc2w, fc2b,
    US(OFF_WHH0F), US(OFF_WHH0R), US(OFF_WIH0F), US(OFF_WIH0R),
    US(OFF_WIH1), US(OFF_WHH1), US(OFF_WIH1R), US(OFF_FC1W), US(OFF_FC2W),
    FP(OFF_BRZ0), FP(OFF_BNIH0), FP(OFF_BNHH0),
    FP(OFF_BRZ1), FP(OFF_BNIH1), FP(OFF_BNHH1),
    FP(OFF_BRZ1R), FP(OFF_BNIH1R), FP(OFF_BNHH1R),
    FP(OFF_SC2), FP(OFF_SH2), FP(OFF_FC2B));

  us* y0b  = US(OFF_Y0B);
  us* y0fc = US(OFF_Y0FC);
  us* gx   = US(OFF_GX);
  us* h0bf = US(OFF_H0BF);
  us* h1bf = US(OFF_H1BF);

  // ---- phase A: layer-0 backward, 7 chunks of 4 steps ----
  for (int c = 0; c < 7; ++c){
    const int t0 = 27 - 4*c;
    // gx0b[sl] = x[:, t0-sl, :] @ Wih0r^T   (M=16384, K=32, nk=1)
    gemm_kernel<<<128*12, 512, 0, stream>>>(
      x + t0*28, -28, nullptr, 0, 0, 32, nullptr, 0, 0, 0,
      US(OFF_WIH0R), 32, 1, 2, 128, gx, PLANE);
    for (int sl = 0; sl < 4; ++sl){
      const int s = 4*c + sl, t = 27 - s;
      gru_serial_kernel<<<256, 512, 0, stream>>>(
        US(OFF_WHH0R), gx + (size_t)sl*PLANE,
        h0bf + (s & 1)*PPH, FP(OFF_H0F32), h0bf + ((s & 1) ^ 1)*PPH,
        y0b + t*512, 28ll*512,
        FP(OFF_BRZ0) + 1024, FP(OFF_BNIH0) + 512, FP(OFF_BNHH0) + 512, s == 0);
    }
  }

  // ---- phase B: layer-0 forward + layer-1 forward, chunk-interleaved ----
  for (int c = 0; c < 7; ++c){
    const int t0 = 4*c;
    // gx0f[sl] = x[:, t0+sl, :] @ Wih0^T
    gemm_kernel<<<128*12, 512, 0, stream>>>(
      x + t0*28, 28, nullptr, 0, 0, 32, nullptr, 0, 0, 0,
      US(OFF_WIH0F), 32, 1, 2, 128, gx, PLANE);
    for (int sl = 0; sl < 4; ++sl){
      const int s = 4*c + sl;
      gru_serial_kernel<<<256, 512, 0, stream>>>(
        US(OFF_WHH0F), gx + (size_t)sl*PLANE,
        h0bf + (s & 1)*PPH, FP(OFF_H0F32), h0bf + ((s & 1) ^ 1)*PPH,
        y0fc + sl*512, 4ll*512,
        FP(OFF_BRZ0), FP(OFF_BNIH0), FP(OFF_BNHH0), s == 0);
    }
    // gx1[sl] = [y0fc[:,sl,:] | y0b[:,t0+sl,:]] @ Wih1^T  (K=1024, nk=32)
    gemm_kernel<<<128*12, 512, 0, stream>>>(
      nullptr, 0,
      y0fc, 4ll*512, 512, 512,
      y0b + t0*512, 28ll*512, 512, 512,
      US(OFF_WIH1), 1024, 32, 2, 128, gx, PLANE);
    for (int sl = 0; sl < 4; ++sl){
      const int s = 4*c + sl;
      gru_serial_kernel<<<256, 512, 0, stream>>>(
        US(OFF_WHH1), gx + (size_t)sl*PLANE,
        h1bf + (s & 1)*PPH, FP(OFF_H1F32), h1bf + ((s & 1) ^ 1)*PPH,
        nullptr, 0,
        FP(OFF_BRZ1), FP(OFF_BNIH1), FP(OFF_BNHH1), s == 0);
    }
  }

  // ---- layer-1 backward: gxb = [h0f_27 | y0b_27] @ Wih1r^T, then gates (h=0) ----
  gemm_kernel<<<32*12, 512, 0, stream>>>(
    nullptr, 0,
    h0bf, 512, 0, 512,                       // h0f final state lives in pp buffer 0
    y0b + 27*512, 28ll*512, 0, 512,
    US(OFF_WIH1R), 1024, 32, 0, 32, gx, 0);
  gate1b_kernel<<<8192, 256, 0, stream>>>(
    gx, FP(OFF_BRZ1R), FP(OFF_BNIH1R), FP(OFF_BNHH1R), US(OFF_H1B));

  // ---- head (h1f final is pp buffer 0 after 28 steps) ----
  head_kernel<<<128, 512, 0, stream>>>(
    h1bf, US(OFF_H1B), US(OFF_FC1W), US(OFF_FC2W),
    FP(OFF_SC2), FP(OFF_SH2), FP(OFF_FC2B), (float*)d_out);
}